// Round 11
// baseline (235.222 us; speedup 1.0000x reference)
//
#include <hip/hip_runtime.h>

#define SEQ 2048
#define BATCH 2
#define DM 1024
#define NH 16
#define DH 64

typedef __bf16 bf16;
typedef __bf16 bf16x8 __attribute__((ext_vector_type(8)));
typedef __bf16 bf16x4 __attribute__((ext_vector_type(4)));
typedef float f32x4 __attribute__((ext_vector_type(4)));

#define MFMA16(a, b, c) __builtin_amdgcn_mfma_f32_16x16x32_bf16((a), (b), (c), 0, 0, 0)

#if __has_builtin(__builtin_amdgcn_exp2f)
#define EXP2(x) __builtin_amdgcn_exp2f(x)
#else
#define EXP2(x) exp2f(x)
#endif

// Q scale folds 1/sqrt(64) and log2(e) so softmax uses bare v_exp_f32 (exp2)
#define QSCALE 0.18033688f

// async global->LDS, 16B per lane; LDS dest = wave-uniform base + lane*16
typedef __attribute__((address_space(3))) void lds_void;
typedef __attribute__((address_space(1))) void glb_void;
__device__ __forceinline__ void gld16(void* lds, const void* g) {
    __builtin_amdgcn_global_load_lds((const glb_void*)g, (lds_void*)lds, 16, 0, 0);
}

// ---------------------------------------------------------------------------
// K0: fused prep (unchanged). cast x -> bf16; W_{Q,K,V} -> wT (flat [3072]
// [1024]); W_O -> woT [d][he].
// ---------------------------------------------------------------------------
__global__ __launch_bounds__(256) void k_prep(const float* __restrict__ x,
                                              const float* __restrict__ WQ,
                                              const float* __restrict__ WK,
                                              const float* __restrict__ WV,
                                              const float* __restrict__ WO,
                                              bf16* __restrict__ xb,
                                              bf16* __restrict__ wT,
                                              bf16* __restrict__ woT) {
    int bx = blockIdx.x;
    int t = threadIdx.x;
    if (bx < 2048) {
        int g = bx * 256 + t;
        const float4* x4 = (const float4*)x;
        float4 a = x4[2 * g];
        float4 b = x4[2 * g + 1];
        bf16x8 o;
        o[0] = (bf16)a.x; o[1] = (bf16)a.y; o[2] = (bf16)a.z; o[3] = (bf16)a.w;
        o[4] = (bf16)b.x; o[5] = (bf16)b.y; o[6] = (bf16)b.z; o[7] = (bf16)b.w;
        *(bf16x8*)(xb + 8 * g) = o;
        return;
    }
    __shared__ bf16 T[64 * 65];
    if (bx < 2816) {
        int id = bx - 2048;
        int kt = id & 15, ph = id >> 4;
        int p = ph >> 4, h = ph & 15;
        const float* Wp = (p == 0) ? WQ : (p == 1) ? WK : WV;
        const float* src = Wp + ((size_t)h * DM + (size_t)kt * 64) * DH;
        for (int i = 0; i < 4; i++) {
            int c = t + 256 * i;
            int r = c >> 4;
            int col = (c & 15) * 4;
            float4 v = *(const float4*)&src[r * 64 + col];
            T[(col + 0) * 65 + r] = (bf16)v.x;
            T[(col + 1) * 65 + r] = (bf16)v.y;
            T[(col + 2) * 65 + r] = (bf16)v.z;
            T[(col + 3) * 65 + r] = (bf16)v.w;
        }
        __syncthreads();
        bf16* dst = wT + (size_t)ph * 64 * DM + (size_t)kt * 64;
        for (int i = 0; i < 2; i++) {
            int c = t + 256 * i;
            int e = c >> 3;
            int k0 = (c & 7) * 8;
            bf16x8 o;
            for (int j = 0; j < 8; j++) o[j] = T[e * 65 + k0 + j];
            *(bf16x8*)&dst[(size_t)e * DM + k0] = o;
        }
    } else {
        int id = bx - 2816;
        int ht = id & 15, dt = id >> 4;
        for (int i = 0; i < 4; i++) {
            int c = t + 256 * i;
            int r = c >> 4;
            int col = (c & 15) * 4;
            float4 v = *(const float4*)&WO[((size_t)(ht * 64 + r)) * DM + dt * 64 + col];
            T[(col + 0) * 65 + r] = (bf16)v.x;
            T[(col + 1) * 65 + r] = (bf16)v.y;
            T[(col + 2) * 65 + r] = (bf16)v.z;
            T[(col + 3) * 65 + r] = (bf16)v.w;
        }
        __syncthreads();
        for (int i = 0; i < 2; i++) {
            int c = t + 256 * i;
            int d = c >> 3;
            int h0 = (c & 7) * 8;
            bf16x8 o;
            for (int j = 0; j < 8; j++) o[j] = T[d * 65 + h0 + j];
            *(bf16x8*)&woT[((size_t)(dt * 64 + d)) * DM + ht * 64 + h0] = o;
        }
    }
}

// ---------------------------------------------------------------------------
// K1: QKV projection (R10 body, unchanged — 256x192 flat tile, 256 blocks).
// ---------------------------------------------------------------------------
__global__ __launch_bounds__(512, 2) void k_qkv(const bf16* __restrict__ xb,
                                                const bf16* __restrict__ wT,
                                                const float* __restrict__ bQ,
                                                const float* __restrict__ bK,
                                                const float* __restrict__ bV,
                                                bf16* __restrict__ Qb,
                                                bf16* __restrict__ Kb,
                                                bf16* __restrict__ VTf) {
    int mt = blockIdx.x, nt = blockIdx.y;
    __shared__ __align__(16) char sm[114688];   // 4 slots x (A 16KB | B 12KB)
    int t = threadIdx.x;
    int lane = t & 63, w = t >> 6;
    int l15 = lane & 15, quad = lane >> 4;
    int wr = w >> 2, wc = w & 3;               // 2M x 4N wave grid
    int m0 = mt * 256;
    int n0 = nt * 192;                          // flat he3 base

    int P0 = t * 16;
    int L0 = P0 ^ (((P0 >> 7) & 3) << 4);
    int row0 = L0 >> 6, kc0 = (L0 >> 4) & 3;
    int P1 = 8192 + t * 16;
    int L1 = P1 ^ (((P1 >> 7) & 3) << 4);
    int row1 = L1 >> 6, kc1 = (L1 >> 4) & 3;
    const bf16* gA0 = xb + (size_t)(m0 + row0) * DM + kc0 * 8;
    const bf16* gA1 = xb + (size_t)(m0 + row1) * DM + kc1 * 8;
    const bf16* gB0 = wT + (size_t)(n0 + row0) * DM + kc0 * 8;
    const bf16* gB1 = wT + (size_t)(n0 + row1) * DM + kc1 * 8;   // valid t<256

    auto stage = [&](int ts, bool bsel) {
        char* sb = sm + (ts & 3) * 28672;
        int ko = ts * 32;
        if (!bsel) {
            gld16(sb + w * 1024, gA0 + ko);
            gld16(sb + 8192 + w * 1024, gA1 + ko);
        } else {
            gld16(sb + 16384 + w * 1024, gB0 + ko);
            if (w < 4) gld16(sb + 16384 + 8192 + w * 1024, gB1 + ko);
        }
    };

    int aoff[8], boff[3];
#pragma unroll
    for (int mi = 0; mi < 8; mi++) {
        int row = wr * 128 + mi * 16 + l15;
        aoff[mi] = row * 64 + ((quad ^ ((row >> 1) & 3)) << 4);
    }
#pragma unroll
    for (int ni = 0; ni < 3; ni++) {
        int row = wc * 48 + ni * 16 + l15;
        boff[ni] = 16384 + row * 64 + ((quad ^ ((row >> 1) & 3)) << 4);
    }

    const f32x4 z4 = {0.f, 0.f, 0.f, 0.f};
    f32x4 acc[8][3];
#pragma unroll
    for (int mi = 0; mi < 8; mi++)
#pragma unroll
        for (int ni = 0; ni < 3; ni++) acc[mi][ni] = z4;

    auto kstep = [&](int tt, bool st) {
        const char* sb = sm + (tt & 3) * 28672;
        bf16x8 bfr[3], afr[4];
#pragma unroll
        for (int ni = 0; ni < 3; ni++) bfr[ni] = *(const bf16x8*)(sb + boff[ni]);
#pragma unroll
        for (int mi = 0; mi < 4; mi++) afr[mi] = *(const bf16x8*)(sb + aoff[mi]);
        if (st) stage(tt + 3, false);
        __builtin_amdgcn_s_setprio(1);
#pragma unroll
        for (int mi = 0; mi < 4; mi++)
#pragma unroll
            for (int ni = 0; ni < 3; ni++)
                acc[mi][ni] = MFMA16(afr[mi], bfr[ni], acc[mi][ni]);
        __builtin_amdgcn_s_setprio(0);
        bf16x8 afr2[4];
#pragma unroll
        for (int mi = 0; mi < 4; mi++) afr2[mi] = *(const bf16x8*)(sb + aoff[4 + mi]);
        if (st) stage(tt + 3, true);
        __builtin_amdgcn_s_setprio(1);
#pragma unroll
        for (int mi = 0; mi < 4; mi++)
#pragma unroll
            for (int ni = 0; ni < 3; ni++)
                acc[4 + mi][ni] = MFMA16(afr2[mi], bfr[ni], acc[4 + mi][ni]);
        __builtin_amdgcn_s_setprio(0);
    };

#define QKV_WAIT(N03, N47)                                              \
    do {                                                                \
        if (w < 4) asm volatile("s_waitcnt vmcnt(" #N03 ")" ::: "memory"); \
        else       asm volatile("s_waitcnt vmcnt(" #N47 ")" ::: "memory"); \
        asm volatile("s_barrier" ::: "memory");                         \
        __builtin_amdgcn_sched_barrier(0);                              \
    } while (0)

    stage(0, false); stage(0, true);
    stage(1, false); stage(1, true);
    stage(2, false); stage(2, true);

#pragma unroll 1
    for (int tt = 0; tt < 29; tt++) {
        QKV_WAIT(8, 6);
        kstep(tt, true);
    }
    QKV_WAIT(8, 6);
    kstep(29, false);
    QKV_WAIT(4, 3);
    kstep(30, false);
    QKV_WAIT(0, 0);
    kstep(31, false);
#undef QKV_WAIT

    int b = mt >> 3;
#pragma unroll
    for (int ni = 0; ni < 3; ni++) {
        int he3 = n0 + wc * 48 + ni * 16 + l15;
        int p = he3 >> 10;
        int he = he3 & 1023;
        int h = he >> 6, e = he & 63;
        if (p < 2) {
            const float* bias = (p == 0) ? bQ : bK;
            bf16* dst = (p == 0) ? Qb : Kb;
            float scale = (p == 0) ? QSCALE : 1.0f;
            float bia = bias[he];
            size_t rb = (size_t)(b * NH + h) * SEQ * DH + e;
#pragma unroll
            for (int mi = 0; mi < 8; mi++)
#pragma unroll
                for (int r = 0; r < 4; r++) {
                    int s = ((m0 + wr * 128 + mi * 16 + quad * 4 + r) & 2047);
                    dst[rb + (size_t)s * DH] = (bf16)((acc[mi][ni][r] + bia) * scale);
                }
        } else {
            int no = (he3 >> 4) & 3;
            float bia = bV[he];
#pragma unroll
            for (int mi = 0; mi < 8; mi++) {
                int kvl = (mt & 7) * 256 + wr * 128 + mi * 16;
                int kt = kvl >> 7;
                int f = (mi >> 1) * 4 + no;
                size_t base = (((size_t)(b * NH + h) * 16 + kt) * 16 + f) * 512
                              + (size_t)((quad << 4) | l15) * 8 + (mi & 1) * 4;
                bf16x4 o;
#pragma unroll
                for (int r = 0; r < 4; r++) o[r] = (bf16)(acc[mi][ni][r] + bia);
                *(bf16x4*)&VTf[base] = o;
            }
        }
    }
}

// ---------------------------------------------------------------------------
// K2: flash attention — R11: kv-split for 3 blocks/CU + uniform 17 steps/CU.
// grid (32 bh, 24 y) = 768 blocks (48KB LDS -> exactly 3/CU). y<8: qt=y,
// full kv range, direct-write (bit-identical to R10). y>=8: (qt,seg) from a
// partition of qt=8..15 into halves [0,h) / [h,qt], h=(qt+1)/2, assigned so
// each CU triple {y, y+8, y+16} sums to exactly 17 steps. Exp2-no-max
// softmax => partials over disjoint kv are ADDITIVE: segment blocks write
// f32 (O, denom) to Pacc slots; ticket atomicAdd (device scope, m20) +
// threadfence (G16) lets the SECOND finisher combine+normalize+write Zb.
// Pairs share an XCD (bid = bh mod 8 in every round). No spin, no extra
// kernel. Per-step pipeline identical to R10.
// ---------------------------------------------------------------------------
__global__ __launch_bounds__(512, 4) void k_attn(const bf16* __restrict__ Qb,
                                                 const bf16* __restrict__ Kb,
                                                 const bf16* __restrict__ VTf,
                                                 bf16* __restrict__ Zb,
                                                 float* __restrict__ Pacc,
                                                 int* __restrict__ Tk) {
    int bh = blockIdx.x;
    int y = blockIdx.y;
    int h = bh & 15, b = bh >> 4;
    __shared__ __align__(16) bf16 Ks[2][16 * 512];   // 32 KB
    __shared__ __align__(16) bf16 Vs[16 * 512];      // 16 KB
    __shared__ int sOld;
    int t = threadIdx.x;
    int lane = t & 63, w = t >> 6;
    int l15 = lane & 15, quad = lane >> 4;

    // --- segment decode: CU triple {y, y+8, y+16} sums to 17 steps ---
    int qt, kt0, kt1, seg;
    if (y < 8) {
        qt = y; kt0 = 0; kt1 = qt; seg = -1;        // lens 1..8
    } else {
        const int qtA[8] = {15, 13, 13, 11, 11, 9, 9, 8};
        const int sgA[8] = {0, 0, 1, 0, 1, 0, 1, 0};   // lens 8,7,7,6,6,5,5,4
        const int qtB[8] = {15, 14, 14, 12, 12, 10, 10, 8};
        const int sgB[8] = {1, 1, 0, 1, 0, 1, 0, 1};   // lens 8,8,7,7,6,6,5,5
        int g = (y - 8) & 7;
        if (y < 16) { qt = qtA[g]; seg = sgA[g]; }
        else        { qt = qtB[g]; seg = sgB[g]; }
        int hh = (qt + 1) >> 1;
        kt0 = seg ? hh : 0;
        kt1 = seg ? qt : hh - 1;
    }

    const bf16* qbase = Qb + (size_t)bh * SEQ * DH;
    const bf16* kbase = Kb + (size_t)bh * SEQ * DH;
    const bf16* vfrag = VTf + (size_t)bh * 16 * 8192;

    int qr0 = qt * 128 + w * 16;
    bf16x8 aq[2];   // Q as B-operand: lane holds q=qr0+l15, e=ks*32+quad*8+j
    for (int ks = 0; ks < 2; ks++)
        aq[ks] = *(const bf16x8*)&qbase[(size_t)(qr0 + l15) * DH + ks * 32 + quad * 8];

    auto stageK = [&](int buf, int kt) {
        for (int i = 0; i < 2; i++) {
            int f = w * 2 + i;
            int ks = f >> 3, ni = f & 7;
            gld16(&Ks[buf][f * 512],
                  kbase + (size_t)(kt * 128 + ni * 16 + l15) * DH + ks * 32 + quad * 8);
        }
    };
    auto stageV = [&](int kt) {
        const bf16* vt = vfrag + (size_t)kt * 8192;
        for (int i = 0; i < 2; i++) {
            int f = w * 2 + i;
            gld16(&Vs[f * 512], vt + f * 512 + lane * 8);
        }
    };

    const bf16 one = (bf16)1.0f;
    const bf16x8 ones = {one, one, one, one, one, one, one, one};
    const f32x4 z4 = {0.f, 0.f, 0.f, 0.f};
    f32x4 acco[4], accd;
    for (int no = 0; no < 4; no++) acco[no] = z4;
    accd = z4;

    stageK(0, kt0);

    for (int kt = kt0; kt <= kt1; kt++) {
        int buf = (kt - kt0) & 1;
        // K[kt] ready (only K outstanding; cover = prev QK+softmax+PV)
        asm volatile("s_waitcnt vmcnt(0)\n\ts_barrier" ::: "memory");
        __builtin_amdgcn_sched_barrier(0);
        stageV(kt);        // V[kt] lands during QK+softmax below
        if (kt < kt1) stageK(buf ^ 1, kt + 1);
        const bf16* Kbuf = Ks[buf];

        // S^T = K x Q^T : lane holds q=l15, kv=ni*16+quad*4+r
        f32x4 accs[8];
        for (int ni = 0; ni < 8; ni++) accs[ni] = z4;
        __builtin_amdgcn_s_setprio(1);
        for (int ks = 0; ks < 2; ks++)
            for (int ni = 0; ni < 8; ni++) {
                bf16x8 ak = *(const bf16x8*)&Kbuf[(ks * 8 + ni) * 512 + lane * 8];
                accs[ni] = MFMA16(ak, aq[ks], accs[ni]);
            }
        __builtin_amdgcn_s_setprio(0);

        if (kt == qt) {   // causal mask (diagonal tile; only reachable seg!=0)
            int ql = w * 16 + l15;
            for (int ni = 0; ni < 8; ni++) {
                int kvl = ni * 16 + quad * 4;
                for (int r = 0; r < 4; r++)
                    if (kvl + r > ql) accs[ni][r] = -1e30f;
            }
        }

        // P^T = exp2(S^T) in registers (no max subtraction -> additive partials)
        bf16x4 pt[8];
        for (int ni = 0; ni < 8; ni++)
            for (int r = 0; r < 4; r++)
                pt[ni][r] = (bf16)EXP2(accs[ni][r]);

        // V[kt] done (FIFO [V,V,K,K]); K[kt+1] may stay in flight through PV
        if (kt < kt1) {
            asm volatile("s_waitcnt vmcnt(2)\n\ts_barrier" ::: "memory");
        } else {
            asm volatile("s_waitcnt vmcnt(0)\n\ts_barrier" ::: "memory");
        }
        __builtin_amdgcn_sched_barrier(0);

        // O += P(A) x V(B); ones-B -> per-lane denominator.
        __builtin_amdgcn_s_setprio(1);
        for (int p4 = 0; p4 < 4; p4++) {
            bf16x8 ap;
            for (int j = 0; j < 4; j++) {
                ap[j] = pt[2 * p4][j];
                ap[4 + j] = pt[2 * p4 + 1][j];
            }
            accd = MFMA16(ap, ones, accd);
            for (int no = 0; no < 4; no++) {
                bf16x8 bv = *(const bf16x8*)&Vs[(p4 * 4 + no) * 512 + lane * 8];
                acco[no] = MFMA16(ap, bv, acco[no]);
            }
        }
        __builtin_amdgcn_s_setprio(0);
    }

    if (seg < 0) {
        // direct path (rows q < 1024): bit-identical to R10
        for (int r = 0; r < 4; r++) {
            float inv = 1.0f / accd[r];
            int q = qr0 + quad * 4 + r;
            size_t rowbase = ((size_t)b * SEQ + q) * DM + h * DH;
            for (int no = 0; no < 4; no++)
                Zb[rowbase + no * 16 + l15] = (bf16)(acco[no][r] * inv);
        }
        return;
    }

    // --- segment path: write f32 partial (O 128x64, D 128) to slot ---
    int qt8 = qt - 8;
    int pairIdx = bh * 8 + qt8;
    size_t s0 = (size_t)(pairIdx * 2) * 8448;       // slot size 8448 floats
    float* Om = Pacc + s0 + (size_t)seg * 8448;
    float* Dm = Om + 8192;
    int qrow = w * 16 + quad * 4;
    for (int r = 0; r < 4; r++) {
        for (int no = 0; no < 4; no++)
            Om[(qrow + r) * 64 + no * 16 + l15] = acco[no][r];
        if (l15 == 0) Dm[qrow + r] = accd[r];
    }
    __syncthreads();                                 // all partial stores issued
    if (t == 0) {
        __threadfence();                             // release partial to device
        sOld = atomicAdd(&Tk[pairIdx], 1);
    }
    __syncthreads();
    if (sOld == 1) {
        // second finisher: combine both segments, normalize, write Zb
        __threadfence();                             // acquire partner's partial
        const float* O0 = Pacc + s0;
        const float* D0 = O0 + 8192;
        const float* O1 = O0 + 8448;
        const float* D1 = O1 + 8192;
        int row = t >> 2;                            // 0..127
        int c0 = (t & 3) * 16;                       // 0,16,32,48
        float inv = 1.0f / (D0[row] + D1[row]);
        int q = qt * 128 + row;
        bf16* dst = &Zb[((size_t)b * SEQ + q) * DM + h * DH + c0];
        for (int j = 0; j < 16; j++)
            dst[j] = (bf16)((O0[row * 64 + c0 + j] + O1[row * 64 + c0 + j]) * inv);
    }
}

// ---------------------------------------------------------------------------
// K3: out[s][d] = Zb @ woT + bO (R10 body, unchanged). 128x128 ring-4,
// grid (32,8) = 256 blocks; natural xcd = mt%8 A-panel locality.
// ---------------------------------------------------------------------------
__global__ __launch_bounds__(256, 2) void k_out(const bf16* __restrict__ Zb,
                                                const bf16* __restrict__ woT,
                                                const float* __restrict__ bO,
                                                float* __restrict__ out) {
    int mt = blockIdx.x, nt = blockIdx.y;
    __shared__ __align__(16) char sm[65536];   // 4 slots x (A 8KB | B 8KB)
    int t = threadIdx.x;
    int lane = t & 63, w = t >> 6;
    int l15 = lane & 15, quad = lane >> 4;
    int wr = w >> 1, wc = w & 1;               // 2M x 2N wave grid
    int m0 = mt * 128, n0 = nt * 128;

    int P0 = t * 16;
    int L0 = P0 ^ (((P0 >> 7) & 3) << 4);
    int row0 = L0 >> 6, kc0 = (L0 >> 4) & 3;
    int P1 = 4096 + t * 16;
    int L1 = P1 ^ (((P1 >> 7) & 3) << 4);
    int row1 = L1 >> 6, kc1 = (L1 >> 4) & 3;
    const bf16* gA0 = Zb + (size_t)(m0 + row0) * DM + kc0 * 8;
    const bf16* gA1 = Zb + (size_t)(m0 + row1) * DM + kc1 * 8;
    const bf16* gB0 = woT + (size_t)(n0 + row0) * DM + kc0 * 8;
    const bf16* gB1 = woT + (size_t)(n0 + row1) * DM + kc1 * 8;

    auto stage = [&](int ts) {
        char* sb = sm + (ts & 3) * 16384;
        int ko = ts * 32;
        gld16(sb + w * 1024, gA0 + ko);
        gld16(sb + 4096 + w * 1024, gA1 + ko);
        gld16(sb + 8192 + w * 1024, gB0 + ko);
        gld16(sb + 8192 + 4096 + w * 1024, gB1 + ko);
    };

    int aoff[4], boff[4];
#pragma unroll
    for (int mi = 0; mi < 4; mi++) {
        int row = wr * 64 + mi * 16 + l15;
        aoff[mi] = row * 64 + ((quad ^ ((row >> 1) & 3)) << 4);
    }
#pragma unroll
    for (int ni = 0; ni < 4; ni++) {
        int row = wc * 64 + ni * 16 + l15;
        boff[ni] = 8192 + row * 64 + ((quad ^ ((row >> 1) & 3)) << 4);
    }

    const f32x4 z4 = {0.f, 0.f, 0.f, 0.f};
    f32x4 acc[4][4];
#pragma unroll
    for (int mi = 0; mi < 4; mi++)
#pragma unroll
        for (int ni = 0; ni < 4; ni++) acc[mi][ni] = z4;

    auto kstep = [&](int tt, bool st) {
        const char* sb = sm + (tt & 3) * 16384;
        bf16x8 bfr[4], afr[4];
#pragma unroll
        for (int ni = 0; ni < 4; ni++) bfr[ni] = *(const bf16x8*)(sb + boff[ni]);
#pragma unroll
        for (int mi = 0; mi < 4; mi++) afr[mi] = *(const bf16x8*)(sb + aoff[mi]);
        if (st) stage(tt + 3);
        __builtin_amdgcn_s_setprio(1);
#pragma unroll
        for (int mi = 0; mi < 4; mi++)
#pragma unroll
            for (int ni = 0; ni < 4; ni++)
                acc[mi][ni] = MFMA16(afr[mi], bfr[ni], acc[mi][ni]);
        __builtin_amdgcn_s_setprio(0);
    };

    stage(0); stage(1); stage(2);   // 12 loads in flight

#pragma unroll 1
    for (int tt = 0; tt < 29; tt++) {
        asm volatile("s_waitcnt vmcnt(8)\n\ts_barrier" ::: "memory");
        __builtin_amdgcn_sched_barrier(0);
        kstep(tt, true);
    }
    asm volatile("s_waitcnt vmcnt(8)\n\ts_barrier" ::: "memory");
    __builtin_amdgcn_sched_barrier(0);
    kstep(29, false);
    asm volatile("s_waitcnt vmcnt(4)\n\ts_barrier" ::: "memory");
    __builtin_amdgcn_sched_barrier(0);
    kstep(30, false);
    asm volatile("s_waitcnt vmcnt(0)\n\ts_barrier" ::: "memory");
    __builtin_amdgcn_sched_barrier(0);
    kstep(31, false);

#pragma unroll
    for (int ni = 0; ni < 4; ni++) {
        int d = n0 + wc * 64 + ni * 16 + l15;
        float bia = bO[d];
#pragma unroll
        for (int mi = 0; mi < 4; mi++)
#pragma unroll
            for (int r = 0; r < 4; r++) {
                int s = m0 + wr * 64 + mi * 16 + quad * 4 + r;
                out[(size_t)s * DM + d] = acc[mi][ni][r] + bia;
            }
    }
}

// ---------------------------------------------------------------------------
extern "C" void kernel_launch(void* const* d_in, const int* in_sizes, int n_in,
                              void* d_out, int out_size, void* d_ws, size_t ws_size,
                              hipStream_t stream) {
    const float* x  = (const float*)d_in[0];
    const float* WQ = (const float*)d_in[1];
    const float* WK = (const float*)d_in[2];
    const float* WV = (const float*)d_in[3];
    const float* WO = (const float*)d_in[4];
    const float* bQ = (const float*)d_in[5];
    const float* bK = (const float*)d_in[6];
    const float* bV = (const float*)d_in[7];
    const float* bO = (const float*)d_in[8];
    float* out = (float*)d_out;

    char* w = (char*)d_ws;
    bf16* xb    = (bf16*)(w + 0);                      //  8 MB [4096][1024]
    bf16* wqkvT = (bf16*)(w + (8u << 20));             //  6 MB flat [3072][1024]
    bf16* woT   = (bf16*)(w + (14u << 20));            //  2 MB [d][he]
    bf16* Qb    = (bf16*)(w + (16u << 20));            //  8 MB [b][h][s][e]
    bf16* Kb    = (bf16*)(w + (24u << 20));            //  8 MB [b][h][s][e]
    bf16* VTf   = (bf16*)(w + (32u << 20));            //  8 MB [bh][kt][16][512]
    bf16* Zb    = (bf16*)(w + (40u << 20));            //  8 MB [b][s][h*64+e]
    float* Pacc = (float*)(w + (48u << 20));           // 17.3 MB partials
    int*  Tk    = (int*)(w + (66u << 20));             //  1 KB tickets

    hipMemsetAsync(Tk, 0, 32 * 8 * sizeof(int), stream);
    k_prep<<<3072, 256, 0, stream>>>(x, WQ, WK, WV, WO, xb, wqkvT, woT);
    k_qkv<<<dim3(16, 16), 512, 0, stream>>>(xb, wqkvT, bQ, bK, bV, Qb, Kb, VTf);
    k_attn<<<dim3(32, 24), 512, 0, stream>>>(Qb, Kb, VTf, Zb, Pacc, Tk);
    k_out<<<dim3(32, 8), 256, 0, stream>>>(Zb, woT, bO, out);
}

// Round 13
// 161.958 us; speedup vs baseline: 1.4524x; 1.4524x over previous
//
#include <hip/hip_runtime.h>

#define SEQ 2048
#define BATCH 2
#define DM 1024
#define NH 16
#define DH 64

typedef __bf16 bf16;
typedef __bf16 bf16x8 __attribute__((ext_vector_type(8)));
typedef __bf16 bf16x4 __attribute__((ext_vector_type(4)));
typedef float f32x4 __attribute__((ext_vector_type(4)));

#define MFMA16(a, b, c) __builtin_amdgcn_mfma_f32_16x16x32_bf16((a), (b), (c), 0, 0, 0)

#if __has_builtin(__builtin_amdgcn_exp2f)
#define EXP2(x) __builtin_amdgcn_exp2f(x)
#else
#define EXP2(x) exp2f(x)
#endif

// Q scale folds 1/sqrt(64) and log2(e) so softmax uses bare v_exp_f32 (exp2)
#define QSCALE 0.18033688f

// async global->LDS, 16B per lane; LDS dest = wave-uniform base + lane*16
typedef __attribute__((address_space(3))) void lds_void;
typedef __attribute__((address_space(1))) void glb_void;
__device__ __forceinline__ void gld16(void* lds, const void* g) {
    __builtin_amdgcn_global_load_lds((const glb_void*)g, (lds_void*)lds, 16, 0, 0);
}

// ---------------------------------------------------------------------------
// K0: fused prep. blocks [0,2048): cast x -> bf16. [2048,2816): transpose
// W_{Q,K,V} -> wT (flat [3072][1024]). [2816,3072): W_O -> woT [d][he].
// ---------------------------------------------------------------------------
__global__ __launch_bounds__(256) void k_prep(const float* __restrict__ x,
                                              const float* __restrict__ WQ,
                                              const float* __restrict__ WK,
                                              const float* __restrict__ WV,
                                              const float* __restrict__ WO,
                                              bf16* __restrict__ xb,
                                              bf16* __restrict__ wT,
                                              bf16* __restrict__ woT) {
    int bx = blockIdx.x;
    int t = threadIdx.x;
    if (bx < 2048) {
        int g = bx * 256 + t;
        const float4* x4 = (const float4*)x;
        float4 a = x4[2 * g];
        float4 b = x4[2 * g + 1];
        bf16x8 o;
        o[0] = (bf16)a.x; o[1] = (bf16)a.y; o[2] = (bf16)a.z; o[3] = (bf16)a.w;
        o[4] = (bf16)b.x; o[5] = (bf16)b.y; o[6] = (bf16)b.z; o[7] = (bf16)b.w;
        *(bf16x8*)(xb + 8 * g) = o;
        return;
    }
    __shared__ bf16 T[64 * 65];
    if (bx < 2816) {
        int id = bx - 2048;
        int kt = id & 15, ph = id >> 4;
        int p = ph >> 4, h = ph & 15;
        const float* Wp = (p == 0) ? WQ : (p == 1) ? WK : WV;
        const float* src = Wp + ((size_t)h * DM + (size_t)kt * 64) * DH;
        for (int i = 0; i < 4; i++) {
            int c = t + 256 * i;
            int r = c >> 4;
            int col = (c & 15) * 4;
            float4 v = *(const float4*)&src[r * 64 + col];
            T[(col + 0) * 65 + r] = (bf16)v.x;
            T[(col + 1) * 65 + r] = (bf16)v.y;
            T[(col + 2) * 65 + r] = (bf16)v.z;
            T[(col + 3) * 65 + r] = (bf16)v.w;
        }
        __syncthreads();
        bf16* dst = wT + (size_t)ph * 64 * DM + (size_t)kt * 64;
        for (int i = 0; i < 2; i++) {
            int c = t + 256 * i;
            int e = c >> 3;
            int k0 = (c & 7) * 8;
            bf16x8 o;
            for (int j = 0; j < 8; j++) o[j] = T[e * 65 + k0 + j];
            *(bf16x8*)&dst[(size_t)e * DM + k0] = o;
        }
    } else {
        int id = bx - 2816;
        int ht = id & 15, dt = id >> 4;
        for (int i = 0; i < 4; i++) {
            int c = t + 256 * i;
            int r = c >> 4;
            int col = (c & 15) * 4;
            float4 v = *(const float4*)&WO[((size_t)(ht * 64 + r)) * DM + dt * 64 + col];
            T[(col + 0) * 65 + r] = (bf16)v.x;
            T[(col + 1) * 65 + r] = (bf16)v.y;
            T[(col + 2) * 65 + r] = (bf16)v.z;
            T[(col + 3) * 65 + r] = (bf16)v.w;
        }
        __syncthreads();
        for (int i = 0; i < 2; i++) {
            int c = t + 256 * i;
            int d = c >> 3;
            int h0 = (c & 7) * 8;
            bf16x8 o;
            for (int j = 0; j < 8; j++) o[j] = T[d * 65 + h0 + j];
            *(bf16x8*)&woT[((size_t)(dt * 64 + d)) * DM + ht * 64 + h0] = o;
        }
    }
}

// ---------------------------------------------------------------------------
// K1: QKV projection (R10 body — 256x192 flat tile over [3072][1024] W,
// grid (16,16) = 256 blocks = full CU coverage, natural xcd = mt%8 A-panel
// locality). BK=32, ring-4 (4 x 28KB = 112KB), stage 3 ahead, counted
// vmcnt + raw s_barrier, setprio, XOR swizzle + pre-swizzled global source.
// B staging 12KB/step: waves 0-3 issue 4 loads/step (vmcnt 8), 4-7 issue 3
// (vmcnt 6). Measured best (R10: 157.5us total).
// ---------------------------------------------------------------------------
__global__ __launch_bounds__(512, 2) void k_qkv(const bf16* __restrict__ xb,
                                                const bf16* __restrict__ wT,
                                                const float* __restrict__ bQ,
                                                const float* __restrict__ bK,
                                                const float* __restrict__ bV,
                                                bf16* __restrict__ Qb,
                                                bf16* __restrict__ Kb,
                                                bf16* __restrict__ VTf) {
    int mt = blockIdx.x, nt = blockIdx.y;
    __shared__ __align__(16) char sm[114688];   // 4 slots x (A 16KB | B 12KB)
    int t = threadIdx.x;
    int lane = t & 63, w = t >> 6;
    int l15 = lane & 15, quad = lane >> 4;
    int wr = w >> 2, wc = w & 3;               // 2M x 4N wave grid
    int m0 = mt * 256;
    int n0 = nt * 192;                          // flat he3 base

    int P0 = t * 16;
    int L0 = P0 ^ (((P0 >> 7) & 3) << 4);
    int row0 = L0 >> 6, kc0 = (L0 >> 4) & 3;
    int P1 = 8192 + t * 16;
    int L1 = P1 ^ (((P1 >> 7) & 3) << 4);
    int row1 = L1 >> 6, kc1 = (L1 >> 4) & 3;
    const bf16* gA0 = xb + (size_t)(m0 + row0) * DM + kc0 * 8;
    const bf16* gA1 = xb + (size_t)(m0 + row1) * DM + kc1 * 8;
    const bf16* gB0 = wT + (size_t)(n0 + row0) * DM + kc0 * 8;
    const bf16* gB1 = wT + (size_t)(n0 + row1) * DM + kc1 * 8;   // valid t<256

    auto stage = [&](int ts, bool bsel) {
        char* sb = sm + (ts & 3) * 28672;
        int ko = ts * 32;
        if (!bsel) {
            gld16(sb + w * 1024, gA0 + ko);
            gld16(sb + 8192 + w * 1024, gA1 + ko);
        } else {
            gld16(sb + 16384 + w * 1024, gB0 + ko);
            if (w < 4) gld16(sb + 16384 + 8192 + w * 1024, gB1 + ko);
        }
    };

    int aoff[8], boff[3];
#pragma unroll
    for (int mi = 0; mi < 8; mi++) {
        int row = wr * 128 + mi * 16 + l15;
        aoff[mi] = row * 64 + ((quad ^ ((row >> 1) & 3)) << 4);
    }
#pragma unroll
    for (int ni = 0; ni < 3; ni++) {
        int row = wc * 48 + ni * 16 + l15;
        boff[ni] = 16384 + row * 64 + ((quad ^ ((row >> 1) & 3)) << 4);
    }

    const f32x4 z4 = {0.f, 0.f, 0.f, 0.f};
    f32x4 acc[8][3];
#pragma unroll
    for (int mi = 0; mi < 8; mi++)
#pragma unroll
        for (int ni = 0; ni < 3; ni++) acc[mi][ni] = z4;

    auto kstep = [&](int tt, bool st) {
        const char* sb = sm + (tt & 3) * 28672;
        bf16x8 bfr[3], afr[4];
#pragma unroll
        for (int ni = 0; ni < 3; ni++) bfr[ni] = *(const bf16x8*)(sb + boff[ni]);
#pragma unroll
        for (int mi = 0; mi < 4; mi++) afr[mi] = *(const bf16x8*)(sb + aoff[mi]);
        if (st) stage(tt + 3, false);
        __builtin_amdgcn_s_setprio(1);
#pragma unroll
        for (int mi = 0; mi < 4; mi++)
#pragma unroll
            for (int ni = 0; ni < 3; ni++)
                acc[mi][ni] = MFMA16(afr[mi], bfr[ni], acc[mi][ni]);
        __builtin_amdgcn_s_setprio(0);
        bf16x8 afr2[4];
#pragma unroll
        for (int mi = 0; mi < 4; mi++) afr2[mi] = *(const bf16x8*)(sb + aoff[4 + mi]);
        if (st) stage(tt + 3, true);
        __builtin_amdgcn_s_setprio(1);
#pragma unroll
        for (int mi = 0; mi < 4; mi++)
#pragma unroll
            for (int ni = 0; ni < 3; ni++)
                acc[4 + mi][ni] = MFMA16(afr2[mi], bfr[ni], acc[4 + mi][ni]);
        __builtin_amdgcn_s_setprio(0);
    };

#define QKV_WAIT(N03, N47)                                              \
    do {                                                                \
        if (w < 4) asm volatile("s_waitcnt vmcnt(" #N03 ")" ::: "memory"); \
        else       asm volatile("s_waitcnt vmcnt(" #N47 ")" ::: "memory"); \
        asm volatile("s_barrier" ::: "memory");                         \
        __builtin_amdgcn_sched_barrier(0);                              \
    } while (0)

    stage(0, false); stage(0, true);
    stage(1, false); stage(1, true);
    stage(2, false); stage(2, true);

#pragma unroll 1
    for (int tt = 0; tt < 29; tt++) {
        QKV_WAIT(8, 6);
        kstep(tt, true);
    }
    QKV_WAIT(8, 6);
    kstep(29, false);
    QKV_WAIT(4, 3);
    kstep(30, false);
    QKV_WAIT(0, 0);
    kstep(31, false);
#undef QKV_WAIT

    int b = mt >> 3;
#pragma unroll
    for (int ni = 0; ni < 3; ni++) {
        int he3 = n0 + wc * 48 + ni * 16 + l15;
        int p = he3 >> 10;
        int he = he3 & 1023;
        int h = he >> 6, e = he & 63;
        if (p < 2) {
            const float* bias = (p == 0) ? bQ : bK;
            bf16* dst = (p == 0) ? Qb : Kb;
            float scale = (p == 0) ? QSCALE : 1.0f;
            float bia = bias[he];
            size_t rb = (size_t)(b * NH + h) * SEQ * DH + e;
#pragma unroll
            for (int mi = 0; mi < 8; mi++)
#pragma unroll
                for (int r = 0; r < 4; r++) {
                    int s = ((m0 + wr * 128 + mi * 16 + quad * 4 + r) & 2047);
                    dst[rb + (size_t)s * DH] = (bf16)((acc[mi][ni][r] + bia) * scale);
                }
        } else {
            int no = (he3 >> 4) & 3;
            float bia = bV[he];
#pragma unroll
            for (int mi = 0; mi < 8; mi++) {
                int kvl = (mt & 7) * 256 + wr * 128 + mi * 16;
                int kt = kvl >> 7;
                int f = (mi >> 1) * 4 + no;
                size_t base = (((size_t)(b * NH + h) * 16 + kt) * 16 + f) * 512
                              + (size_t)((quad << 4) | l15) * 8 + (mi & 1) * 4;
                bf16x4 o;
#pragma unroll
                for (int r = 0; r < 4; r++) o[r] = (bf16)(acc[mi][ni][r] + bia);
                *(bf16x4*)&VTf[base] = o;
            }
        }
    }
}

// ---------------------------------------------------------------------------
// K2: flash attention (R7/R10 body — measured optimum; R3/R8/R11 variants
// all regressed). 48 KB LDS; grid (32,16) = 512 blocks, 2/CU average with
// uniform 17-step CU pairs via (y, y+8) round-robin. K dbuf + single V buf;
// split counted-vmcnt waits (top vmcnt(0), V-wait vmcnt(2) keeps K[kt+1]
// in flight through PV); setprio around QK and PV MFMA clusters.
// ---------------------------------------------------------------------------
__global__ __launch_bounds__(512, 4) void k_attn(const bf16* __restrict__ Qb,
                                                 const bf16* __restrict__ Kb,
                                                 const bf16* __restrict__ VTf,
                                                 bf16* __restrict__ Zb) {
    int bh = blockIdx.x;
    int y = blockIdx.y;
    int qt = (y < 8) ? y : 23 - y;
    int h = bh & 15, b = bh >> 4;
    __shared__ __align__(16) bf16 Ks[2][16 * 512];   // 32 KB
    __shared__ __align__(16) bf16 Vs[16 * 512];      // 16 KB
    int t = threadIdx.x;
    int lane = t & 63, w = t >> 6;
    int l15 = lane & 15, quad = lane >> 4;

    const bf16* qbase = Qb + (size_t)bh * SEQ * DH;
    const bf16* kbase = Kb + (size_t)bh * SEQ * DH;
    const bf16* vfrag = VTf + (size_t)bh * 16 * 8192;

    int qr0 = qt * 128 + w * 16;
    bf16x8 aq[2];   // Q as B-operand: lane holds q=qr0+l15, e=ks*32+quad*8+j
    for (int ks = 0; ks < 2; ks++)
        aq[ks] = *(const bf16x8*)&qbase[(size_t)(qr0 + l15) * DH + ks * 32 + quad * 8];

    auto stageK = [&](int buf, int kt) {
        for (int i = 0; i < 2; i++) {
            int f = w * 2 + i;
            int ks = f >> 3, ni = f & 7;
            gld16(&Ks[buf][f * 512],
                  kbase + (size_t)(kt * 128 + ni * 16 + l15) * DH + ks * 32 + quad * 8);
        }
    };
    auto stageV = [&](int kt) {
        const bf16* vt = vfrag + (size_t)kt * 8192;
        for (int i = 0; i < 2; i++) {
            int f = w * 2 + i;
            gld16(&Vs[f * 512], vt + f * 512 + lane * 8);
        }
    };

    const bf16 one = (bf16)1.0f;
    const bf16x8 ones = {one, one, one, one, one, one, one, one};
    const f32x4 z4 = {0.f, 0.f, 0.f, 0.f};
    f32x4 acco[4], accd;
    for (int no = 0; no < 4; no++) acco[no] = z4;
    accd = z4;

    stageK(0, 0);

    for (int kt = 0; kt <= qt; kt++) {
        int buf = kt & 1;
        // K[kt] ready (only K outstanding; cover = prev QK+softmax+PV)
        asm volatile("s_waitcnt vmcnt(0)\n\ts_barrier" ::: "memory");
        __builtin_amdgcn_sched_barrier(0);
        stageV(kt);        // V[kt] lands during QK+softmax below
        if (kt < qt) stageK(buf ^ 1, kt + 1);
        const bf16* Kbuf = Ks[buf];

        // S^T = K x Q^T : lane holds q=l15, kv=ni*16+quad*4+r
        f32x4 accs[8];
        for (int ni = 0; ni < 8; ni++) accs[ni] = z4;
        __builtin_amdgcn_s_setprio(1);
        for (int ks = 0; ks < 2; ks++)
            for (int ni = 0; ni < 8; ni++) {
                bf16x8 ak = *(const bf16x8*)&Kbuf[(ks * 8 + ni) * 512 + lane * 8];
                accs[ni] = MFMA16(ak, aq[ks], accs[ni]);
            }
        __builtin_amdgcn_s_setprio(0);

        if (kt == qt) {   // causal mask on diagonal tile
            int ql = w * 16 + l15;
            for (int ni = 0; ni < 8; ni++) {
                int kvl = ni * 16 + quad * 4;
                for (int r = 0; r < 4; r++)
                    if (kvl + r > ql) accs[ni][r] = -1e30f;
            }
        }

        // P^T = exp2(S^T) in registers
        bf16x4 pt[8];
        for (int ni = 0; ni < 8; ni++)
            for (int r = 0; r < 4; r++)
                pt[ni][r] = (bf16)EXP2(accs[ni][r]);

        // V[kt] done (FIFO [V,V,K,K]); K[kt+1] may stay in flight through PV
        if (kt < qt) {
            asm volatile("s_waitcnt vmcnt(2)\n\ts_barrier" ::: "memory");
        } else {
            asm volatile("s_waitcnt vmcnt(0)\n\ts_barrier" ::: "memory");
        }
        __builtin_amdgcn_sched_barrier(0);

        // O += P(A) x V(B); V frags linear b128. ones-B -> per-lane denominator.
        __builtin_amdgcn_s_setprio(1);
        for (int p4 = 0; p4 < 4; p4++) {
            bf16x8 ap;
            for (int j = 0; j < 4; j++) {
                ap[j] = pt[2 * p4][j];
                ap[4 + j] = pt[2 * p4 + 1][j];
            }
            accd = MFMA16(ap, ones, accd);
            for (int no = 0; no < 4; no++) {
                bf16x8 bv = *(const bf16x8*)&Vs[(p4 * 4 + no) * 512 + lane * 8];
                acco[no] = MFMA16(ap, bv, acco[no]);
            }
        }
        __builtin_amdgcn_s_setprio(0);
    }

    // epilogue: O[q][e], per-lane denominator; 32B runs along e
    for (int r = 0; r < 4; r++) {
        float inv = 1.0f / accd[r];
        int q = qr0 + quad * 4 + r;
        size_t rowbase = ((size_t)b * SEQ + q) * DM + h * DH;
        for (int no = 0; no < 4; no++)
            Zb[rowbase + no * 16 + l15] = (bf16)(acco[no][r] * inv);
    }
}

// ---------------------------------------------------------------------------
// K3: out[s][d] = Zb @ woT + bO (R10 body). 128x128 ring-4 pipeline,
// grid (32,8) = 256 blocks; natural xcd = mt%8 A-panel locality.
// ---------------------------------------------------------------------------
__global__ __launch_bounds__(256, 2) void k_out(const bf16* __restrict__ Zb,
                                                const bf16* __restrict__ woT,
                                                const float* __restrict__ bO,
                                                float* __restrict__ out) {
    int mt = blockIdx.x, nt = blockIdx.y;
    __shared__ __align__(16) char sm[65536];   // 4 slots x (A 8KB | B 8KB)
    int t = threadIdx.x;
    int lane = t & 63, w = t >> 6;
    int l15 = lane & 15, quad = lane >> 4;
    int wr = w >> 1, wc = w & 1;               // 2M x 2N wave grid
    int m0 = mt * 128, n0 = nt * 128;

    int P0 = t * 16;
    int L0 = P0 ^ (((P0 >> 7) & 3) << 4);
    int row0 = L0 >> 6, kc0 = (L0 >> 4) & 3;
    int P1 = 4096 + t * 16;
    int L1 = P1 ^ (((P1 >> 7) & 3) << 4);
    int row1 = L1 >> 6, kc1 = (L1 >> 4) & 3;
    const bf16* gA0 = Zb + (size_t)(m0 + row0) * DM + kc0 * 8;
    const bf16* gA1 = Zb + (size_t)(m0 + row1) * DM + kc1 * 8;
    const bf16* gB0 = woT + (size_t)(n0 + row0) * DM + kc0 * 8;
    const bf16* gB1 = woT + (size_t)(n0 + row1) * DM + kc1 * 8;

    auto stage = [&](int ts) {
        char* sb = sm + (ts & 3) * 16384;
        int ko = ts * 32;
        gld16(sb + w * 1024, gA0 + ko);
        gld16(sb + 4096 + w * 1024, gA1 + ko);
        gld16(sb + 8192 + w * 1024, gB0 + ko);
        gld16(sb + 8192 + 4096 + w * 1024, gB1 + ko);
    };

    int aoff[4], boff[4];
#pragma unroll
    for (int mi = 0; mi < 4; mi++) {
        int row = wr * 64 + mi * 16 + l15;
        aoff[mi] = row * 64 + ((quad ^ ((row >> 1) & 3)) << 4);
    }
#pragma unroll
    for (int ni = 0; ni < 4; ni++) {
        int row = wc * 64 + ni * 16 + l15;
        boff[ni] = 8192 + row * 64 + ((quad ^ ((row >> 1) & 3)) << 4);
    }

    const f32x4 z4 = {0.f, 0.f, 0.f, 0.f};
    f32x4 acc[4][4];
#pragma unroll
    for (int mi = 0; mi < 4; mi++)
#pragma unroll
        for (int ni = 0; ni < 4; ni++) acc[mi][ni] = z4;

    auto kstep = [&](int tt, bool st) {
        const char* sb = sm + (tt & 3) * 16384;
        bf16x8 bfr[4], afr[4];
#pragma unroll
        for (int ni = 0; ni < 4; ni++) bfr[ni] = *(const bf16x8*)(sb + boff[ni]);
#pragma unroll
        for (int mi = 0; mi < 4; mi++) afr[mi] = *(const bf16x8*)(sb + aoff[mi]);
        if (st) stage(tt + 3);
        __builtin_amdgcn_s_setprio(1);
#pragma unroll
        for (int mi = 0; mi < 4; mi++)
#pragma unroll
            for (int ni = 0; ni < 4; ni++)
                acc[mi][ni] = MFMA16(afr[mi], bfr[ni], acc[mi][ni]);
        __builtin_amdgcn_s_setprio(0);
    };

    stage(0); stage(1); stage(2);   // 12 loads in flight

#pragma unroll 1
    for (int tt = 0; tt < 29; tt++) {
        asm volatile("s_waitcnt vmcnt(8)\n\ts_barrier" ::: "memory");
        __builtin_amdgcn_sched_barrier(0);
        kstep(tt, true);
    }
    asm volatile("s_waitcnt vmcnt(8)\n\ts_barrier" ::: "memory");
    __builtin_amdgcn_sched_barrier(0);
    kstep(29, false);
    asm volatile("s_waitcnt vmcnt(4)\n\ts_barrier" ::: "memory");
    __builtin_amdgcn_sched_barrier(0);
    kstep(30, false);
    asm volatile("s_waitcnt vmcnt(0)\n\ts_barrier" ::: "memory");
    __builtin_amdgcn_sched_barrier(0);
    kstep(31, false);

#pragma unroll
    for (int ni = 0; ni < 4; ni++) {
        int d = n0 + wc * 64 + ni * 16 + l15;
        float bia = bO[d];
#pragma unroll
        for (int mi = 0; mi < 4; mi++)
#pragma unroll
            for (int r = 0; r < 4; r++) {
                int s = m0 + wr * 64 + mi * 16 + quad * 4 + r;
                out[(size_t)s * DM + d] = acc[mi][ni][r] + bia;
            }
    }
}

// ---------------------------------------------------------------------------
extern "C" void kernel_launch(void* const* d_in, const int* in_sizes, int n_in,
                              void* d_out, int out_size, void* d_ws, size_t ws_size,
                              hipStream_t stream) {
    const float* x  = (const float*)d_in[0];
    const float* WQ = (const float*)d_in[1];
    const float* WK = (const float*)d_in[2];
    const float* WV = (const float*)d_in[3];
    const float* WO = (const float*)d_in[4];
    const float* bQ = (const float*)d_in[5];
    const float* bK = (const float*)d_in[6];
    const float* bV = (const float*)d_in[7];
    const float* bO = (const float*)d_in[8];
    float* out = (float*)d_out;

    char* w = (char*)d_ws;
    bf16* xb    = (bf16*)(w + 0);                      //  8 MB [4096][1024]
    bf16* wqkvT = (bf16*)(w + (8u << 20));             //  6 MB flat [3072][1024]
    bf16* woT   = (bf16*)(w + (14u << 20));            //  2 MB [d][he]
    bf16* Qb    = (bf16*)(w + (16u << 20));            //  8 MB [b][h][s][e]
    bf16* Kb    = (bf16*)(w + (24u << 20));            //  8 MB [b][h][s][e]
    bf16* VTf   = (bf16*)(w + (32u << 20));            //  8 MB [bh][kt][16][512]
    bf16* Zb    = (bf16*)(w + (40u << 20));            //  8 MB [b][s][h*64+e]

    k_prep<<<3072, 256, 0, stream>>>(x, WQ, WK, WV, WO, xb, wqkvT, woT);
    k_qkv<<<dim3(16, 16), 512, 0, stream>>>(xb, wqkvT, bQ, bK, bV, Qb, Kb, VTf);
    k_attn<<<dim3(32, 16), 512, 0, stream>>>(Qb, Kb, VTf, Zb);
    k_out<<<dim3(32, 8), 256, 0, stream>>>(Zb, woT, bO, out);
}